// Round 17
// baseline (214.226 us; speedup 1.0000x reference)
//
#include <hip/hip_runtime.h>

typedef __attribute__((ext_vector_type(8))) short short8;
typedef __attribute__((ext_vector_type(4))) float f32x4;

#define MFMA16(a, b, c) __builtin_amdgcn_mfma_f32_16x16x32_bf16(a, b, c, 0, 0, 0)

__device__ __forceinline__ ushort bf16_rne(float f) {
  uint u = __float_as_uint(f);
  u += 0x7FFFu + ((u >> 16) & 1u);
  return (ushort)(u >> 16);
}

__device__ __forceinline__ void gload_lds16(const void* g, void* l) {
  __builtin_amdgcn_global_load_lds((const __attribute__((address_space(1))) uint*)g,
                                   (__attribute__((address_space(3))) uint*)l, 16, 0, 0);
}

// ---------------- merged weight split (3 tensors in one launch) ----------------
__global__ void split_w_all_kernel(const float* __restrict__ W1, ushort* __restrict__ w1h,
                                   ushort* __restrict__ w1l, const float* __restrict__ W2,
                                   ushort* __restrict__ w2h, ushort* __restrict__ w2l,
                                   const float* __restrict__ W3, ushort* __restrict__ w3h,
                                   ushort* __restrict__ w3l) {
  int i = blockIdx.x * 256 + threadIdx.x;
  const float* W;
  ushort *hi, *lo;
  int Nr, K, Kp;
  if (i < 128 * 704) {
    W = W1; hi = w1h; lo = w1l; Nr = 128; K = 700; Kp = 704;
  } else if (i < 128 * 704 + 256 * 128) {
    i -= 128 * 704;
    W = W2; hi = w2h; lo = w2l; Nr = 256; K = 128; Kp = 128;
  } else {
    i -= 128 * 704 + 256 * 128;
    W = W3; hi = w3h; lo = w3l; Nr = 20; K = 256; Kp = 256;
  }
  int r = i / Kp, k = i - r * Kp;
  float v = (r < Nr && k < K) ? W[(size_t)r * K + k] : 0.f;
  ushort h = bf16_rne(v);
  float hf = __uint_as_float(((uint)h) << 16);
  ushort l = bf16_rne(v - hf);
  hi[i] = h;
  lo[i] = l;
}

// ---------------- GEMM1 v7: double-buffered LDS, 1 barrier per K-step (T3 min-2phase) ----
// 512 threads (8 waves, 32x32 out each), BK=64, dbuf 96 KB -> 1 block/CU. Same swizzles,
// gload_lds B staging, and packed 3-pass split convert as v4 (bit-identical numerics).
// STAGE(ks+1) issued BEFORE ds_read+MFMA(ks); single __syncthreads per step gives every
// load a full MFMA phase of cover before its drain.
__global__ __launch_bounds__(512, 1) void gemm1_kernel(const float* __restrict__ A,
                                                       const ushort* __restrict__ Bh,
                                                       const ushort* __restrict__ Bl,
                                                       float* __restrict__ C) {
  __shared__ ushort sAh[2][64 * 64];
  __shared__ ushort sAl[2][64 * 64];
  __shared__ ushort sBh[2][128 * 64];
  __shared__ ushort sBl[2][128 * 64];

  const int tid = threadIdx.x;
  const int lane = tid & 63;
  const int w = tid >> 6;        // 0..7
  const int wr = w >> 2, wc = w & 3;  // wave tile: rows wr*32, cols wc*32
  const int m0 = blockIdx.x * 64;
  const int ar = tid >> 3, ag = tid & 7;  // A staging: row 0..63, col-group 0..7

  // B staging: wave w covers rows w*16 + round*8 + (lane>>3); linear LDS dest,
  // pre-swizzled global source ((lane&7)^(lane>>3), since row&7 == lane>>3).
  const int br8 = lane >> 3;
  const int bswz = (((lane & 7) ^ br8) << 3);

  f32x4 acc[2][2];
#pragma unroll
  for (int i = 0; i < 2; ++i)
#pragma unroll
    for (int j = 0; j < 2; ++j) acc[i][j] = f32x4{0.f, 0.f, 0.f, 0.f};

  float4 pf[2];
  auto load_a = [&](int ks) {
    const int k = ks * 64 + ag * 8;
    const float* ap = A + (size_t)(m0 + ar) * 700 + k;
    float4 z;
    z.x = z.y = z.z = z.w = 0.f;
    pf[0] = (k + 3 < 700) ? *(const float4*)ap : z;
    pf[1] = (k + 7 < 700) ? *(const float4*)(ap + 4) : z;
  };
  auto stage_b = [&](int ks, int buf) {
#pragma unroll
    for (int round = 0; round < 2; ++round) {
      const int rbase = w * 16 + round * 8;
      const size_t go = (size_t)(rbase + br8) * 704 + ks * 64 + bswz;
      gload_lds16(Bh + go, &sBh[buf][rbase * 64]);
      gload_lds16(Bl + go, &sBl[buf][rbase * 64]);
    }
  };
  auto stage_a = [&](int buf) {  // convert pf -> LDS (trunc-hi + RNE-lo, packed)
    const float vf[8] = {pf[0].x, pf[0].y, pf[0].z, pf[0].w, pf[1].x, pf[1].y, pf[1].z, pf[1].w};
    uint hw[4], lw[4];
#pragma unroll
    for (int q = 0; q < 4; ++q) {
      const uint u0 = __float_as_uint(vf[2 * q]);
      const uint u1 = __float_as_uint(vf[2 * q + 1]);
      hw[q] = __builtin_amdgcn_perm(u1, u0, 0x07060302u);  // {u0.hi16, u1.hi16}
      const float d0 = vf[2 * q] - __uint_as_float(u0 & 0xFFFF0000u);
      const float d1 = vf[2 * q + 1] - __uint_as_float(u1 & 0xFFFF0000u);
      asm("v_cvt_pk_bf16_f32 %0, %1, %2" : "=v"(lw[q]) : "v"(d0), "v"(d1));
    }
    const int off = ar * 64 + ((ag ^ (ar & 7)) << 3);
    uint4 qh, ql;
    qh.x = hw[0]; qh.y = hw[1]; qh.z = hw[2]; qh.w = hw[3];
    ql.x = lw[0]; ql.y = lw[1]; ql.z = lw[2]; ql.w = lw[3];
    *(uint4*)&sAh[buf][off] = qh;
    *(uint4*)&sAl[buf][off] = ql;
  };

  // ---- prologue: stage tile 0 into buf 0; prefetch A(1) regs ----
  load_a(0);
  stage_b(0, 0);
  stage_a(0);
  load_a(1);
  __syncthreads();  // one-time exposed drain (A(1) included; acceptable once)

  for (int ks = 0; ks < 11; ++ks) {
    const int cur = ks & 1;
    // ---- STAGE(ks+1) -> buf^1: issued before compute, full MFMA cover ----
    if (ks < 10) {
      stage_b(ks + 1, 1 - cur);
      stage_a(1 - cur);  // consumes A(ks+1) regs (landed during prior MFMA phase)
    }
    if (ks < 9) load_a(ks + 2);  // flies under this step's MFMA

    // ---- compute from buf[cur]: 24 MFMA/wave ----
#pragma unroll
    for (int ku = 0; ku < 2; ++ku) {
      const int g0 = ku * 4 + (lane >> 4);
      short8 ah[2], al[2], bh[2], bl[2];
#pragma unroll
      for (int i = 0; i < 2; ++i) {
        const int r = wr * 32 + i * 16 + (lane & 15);
        const int off = r * 64 + ((g0 ^ (r & 7)) << 3);
        ah[i] = *(const short8*)&sAh[cur][off];
        al[i] = *(const short8*)&sAl[cur][off];
      }
#pragma unroll
      for (int j = 0; j < 2; ++j) {
        const int r = wc * 32 + j * 16 + (lane & 15);
        const int off = r * 64 + ((g0 ^ (r & 7)) << 3);
        bh[j] = *(const short8*)&sBh[cur][off];
        bl[j] = *(const short8*)&sBl[cur][off];
      }
#pragma unroll
      for (int i = 0; i < 2; ++i)
#pragma unroll
        for (int j = 0; j < 2; ++j) {
          acc[i][j] = MFMA16(ah[i], bh[j], acc[i][j]);
          acc[i][j] = MFMA16(al[i], bh[j], acc[i][j]);
          acc[i][j] = MFMA16(ah[i], bl[j], acc[i][j]);
        }
    }
    __syncthreads();  // single barrier/step: drains loads issued at step top (MFMA-covered)
  }

#pragma unroll
  for (int i = 0; i < 2; ++i) {
    const int rbase = m0 + wr * 32 + i * 16 + ((lane >> 4) << 2);
#pragma unroll
    for (int j = 0; j < 2; ++j) {
      const int col = wc * 32 + j * 16 + (lane & 15);
#pragma unroll
      for (int rg = 0; rg < 4; ++rg)
        C[(size_t)(rbase + rg) * 128 + col] = acc[i][j][rg];
    }
  }
}

// ---------------- fused layers 2+3 v4 (FROZEN from R12/R16) ----------------
__global__ __launch_bounds__(512, 2) void fused_l23_kernel(
    const float* __restrict__ cur1, const float* __restrict__ b1,
    const ushort* __restrict__ w2h, const ushort* __restrict__ w2l, const float* __restrict__ b2,
    const ushort* __restrict__ w3h, const ushort* __restrict__ w3l, const float* __restrict__ b3,
    const float* __restrict__ beta1p, const float* __restrict__ beta2p,
    const float* __restrict__ beta3p, const float* __restrict__ thr1p,
    const float* __restrict__ thr2p, const float* __restrict__ thr3p,
    float* __restrict__ out) {
  __shared__ __align__(16) char smem[156672];
  float* buf = (float*)smem;
  ushort* s1 = (ushort*)(smem + 32768);
  float* c2 = (float*)(smem + 49152);
  ushort* s2 = (ushort*)(smem + 49152);
  ushort* w3p = (ushort*)(smem + 114688);
  float* c3 = (float*)(smem + 147456);

  const int tid = threadIdx.x;
  const int lane = tid & 63;
  const int w = tid >> 6;
  const int b = blockIdx.x;
  const int lr = lane & 15, lg = lane >> 4;

  const float be1 = fminf(fmaxf(beta1p[0], 0.f), 1.f), th1 = thr1p[0];
  const float be2 = fminf(fmaxf(beta2p[0], 0.f), 1.f), th2 = thr2p[0];
  const float be3 = fminf(fmaxf(beta3p[0], 0.f), 1.f), th3 = thr3p[0];
  const float bi1 = (tid < 128) ? b1[tid] : 0.f;
  const float bi2 = (tid < 256) ? b2[tid] : 0.f;
  const float bi3 = (tid >= 128 && tid < 148) ? b3[tid - 128] : 0.f;

  short8 w2fh[2][4], w2fl[2][4];
#pragma unroll
  for (int j = 0; j < 2; ++j)
#pragma unroll
    for (int ks = 0; ks < 4; ++ks) {
      const size_t o = (size_t)(w * 32 + j * 16 + lr) * 128 + ks * 32 + lg * 8;
      w2fh[j][ks] = *(const short8*)(w2h + o);
      w2fl[j][ks] = *(const short8*)(w2l + o);
    }
#pragma unroll
  for (int p = 0; p < 2; ++p) {
    const int r = p * 16 + (tid >> 5);
    const int g = tid & 31;
    const int swz = ((g ^ (r & 7)) << 3);
    *(uint4*)&w3p[r * 256 + g * 8] = *(const uint4*)(w3h + r * 256 + swz);
    *(uint4*)&w3p[8192 + r * 256 + g * 8] = *(const uint4*)(w3l + r * 256 + swz);
  }
  const float4* cg4 = (const float4*)cur1 + (size_t)b * 16000;
#pragma unroll
  for (int i = 0; i < 4; ++i) ((float4*)buf)[i * 512 + tid] = cg4[i * 512 + tid];
  __syncthreads();

  float m1 = 0.f, m2 = 0.f, m3 = 0.f, a3 = 0.f;

  for (int c = 0; c < 8; ++c) {
    const int t0 = c * 64;

    if (tid < 128) {
      const int g = tid >> 3, nb = tid & 7;
#pragma unroll
      for (int hh = 0; hh < 2; ++hh) {
        float v[32];
#pragma unroll
        for (int u = 0; u < 32; ++u) v[u] = buf[(hh * 32 + u) * 128 + tid];
#pragma unroll
        for (int u = 0; u < 32; ++u) {
          const int row = hh * 32 + u;
          const int t = t0 + row;
          ushort sp = 0;
          if (t < 500) {
            float r = (m1 > th1) ? th1 : 0.f;
            m1 = be1 * m1 + (v[u] + bi1) - r;
            sp = (m1 > th1) ? (ushort)0x3F80 : (ushort)0;
          }
          s1[row * 128 + ((g ^ (row & 7)) << 3) + nb] = sp;
        }
      }
    } else if (tid < 148 && c > 0) {
      const int n = tid - 128;
      const int tp = (c - 1) * 64;
#pragma unroll 8
      for (int u = 0; u < 64; ++u) {
        if (tp + u < 500) {
          const float v = c3[u * 36 + n];
          float r = (m3 > th3) ? th3 : 0.f;
          m3 = be3 * m3 + (v + bi3) - r;
          a3 += (m3 > th3) ? 1.f : 0.f;
        }
      }
    }
    __syncthreads();

    {
      f32x4 acc[4][2];
#pragma unroll
      for (int i = 0; i < 4; ++i)
#pragma unroll
        for (int j = 0; j < 2; ++j) acc[i][j] = f32x4{0.f, 0.f, 0.f, 0.f};
#pragma unroll
      for (int ks = 0; ks < 4; ++ks) {
        const int G = ks * 4 + lg;
        short8 ah[4];
#pragma unroll
        for (int i = 0; i < 4; ++i) {
          const int r = i * 16 + lr;
          ah[i] = *(const short8*)&s1[r * 128 + ((G ^ (r & 7)) << 3)];
        }
#pragma unroll
        for (int j = 0; j < 2; ++j)
#pragma unroll
          for (int i = 0; i < 4; ++i) {
            acc[i][j] = MFMA16(ah[i], w2fh[j][ks], acc[i][j]);
            acc[i][j] = MFMA16(ah[i], w2fl[j][ks], acc[i][j]);
          }
      }
#pragma unroll
      for (int i = 0; i < 4; ++i) {
        const int rbase = i * 16 + (lg << 2);
#pragma unroll
        for (int j = 0; j < 2; ++j) {
          const int col = w * 32 + j * 16 + lr;
#pragma unroll
          for (int rg = 0; rg < 4; ++rg) {
            const int row = rbase + rg;
            c2[row * 256 + (col ^ ((row & 7) << 2))] = acc[i][j][rg];
          }
        }
      }
    }
    __syncthreads();

    float v[32];
    if (tid < 256) {
#pragma unroll
      for (int u = 0; u < 32; ++u) v[u] = c2[u * 256 + (tid ^ ((u & 7) << 2))];
    } else if (c < 7) {
      const int base = (c + 1) * 2048;
#pragma unroll
      for (int i = 0; i < 8; ++i)
        ((float4*)buf)[i * 256 + (tid - 256)] = cg4[base + i * 256 + (tid - 256)];
    }
    __syncthreads();

    if (tid < 256) {
      const int g = tid >> 3, nb = tid & 7;
#pragma unroll
      for (int u = 0; u < 32; ++u) {
        const int t = t0 + u;
        ushort sp = 0;
        if (t < 500) {
          float r = (m2 > th2) ? th2 : 0.f;
          m2 = be2 * m2 + (v[u] + bi2) - r;
          sp = (m2 > th2) ? (ushort)0x3F80 : (ushort)0;
        }
        s2[u * 256 + ((g ^ (u & 7)) << 3) + nb] = sp;
      }
#pragma unroll
      for (int u = 0; u < 32; ++u) v[u] = c2[(32 + u) * 256 + (tid ^ ((u & 7) << 2))];
#pragma unroll
      for (int u = 0; u < 32; ++u) {
        const int row = 32 + u;
        const int t = t0 + row;
        ushort sp = 0;
        if (t < 500) {
          float r = (m2 > th2) ? th2 : 0.f;
          m2 = be2 * m2 + (v[u] + bi2) - r;
          sp = (m2 > th2) ? (ushort)0x3F80 : (ushort)0;
        }
        s2[row * 256 + ((g ^ (row & 7)) << 3) + nb] = sp;
      }
    }
    __syncthreads();

    {
      const int wr3 = w >> 1, wc3 = w & 1;
      f32x4 a3c = f32x4{0.f, 0.f, 0.f, 0.f};
#pragma unroll
      for (int ku = 0; ku < 8; ++ku) {
        const int G = ku * 4 + lg;
        const int rb = wc3 * 16 + lr;
        const int ob = rb * 256 + ((G ^ (rb & 7)) << 3);
        short8 vbh = *(const short8*)&w3p[ob];
        short8 vbl = *(const short8*)&w3p[8192 + ob];
        const int r = wr3 * 16 + lr;
        short8 av = *(const short8*)&s2[r * 256 + ((G ^ (r & 7)) << 3)];
        a3c = MFMA16(av, vbh, a3c);
        a3c = MFMA16(av, vbl, a3c);
      }
      const int rb3 = wr3 * 16 + (lg << 2);
      const int col3 = wc3 * 16 + lr;
#pragma unroll
      for (int rg = 0; rg < 4; ++rg) c3[(rb3 + rg) * 36 + col3] = a3c[rg];
    }
    __syncthreads();
  }

  if (tid >= 128 && tid < 148) {
    const int n = tid - 128;
#pragma unroll 8
    for (int u = 0; u < 64; ++u) {
      if (448 + u < 500) {
        const float v = c3[u * 36 + n];
        float r = (m3 > th3) ? th3 : 0.f;
        m3 = be3 * m3 + (v + bi3) - r;
        a3 += (m3 > th3) ? 1.f : 0.f;
      }
    }
    out[(size_t)b * 20 + n] = a3 * (1.f / 500.f);
  }
}

extern "C" void kernel_launch(void* const* d_in, const int* in_sizes, int n_in, void* d_out,
                              int out_size, void* d_ws, size_t ws_size, hipStream_t stream) {
  const float* x = (const float*)d_in[0];
  const float* W1 = (const float*)d_in[1];
  const float* b1 = (const float*)d_in[2];
  const float* W2 = (const float*)d_in[3];
  const float* b2 = (const float*)d_in[4];
  const float* W3 = (const float*)d_in[5];
  const float* b3 = (const float*)d_in[6];
  const float* beta1 = (const float*)d_in[7];
  const float* beta2 = (const float*)d_in[8];
  const float* beta3 = (const float*)d_in[9];
  const float* thr1 = (const float*)d_in[10];
  const float* thr2 = (const float*)d_in[11];
  const float* thr3 = (const float*)d_in[12];
  float* out = (float*)d_out;

  const int M = 128000;  // B*T
  char* ws = (char*)d_ws;
  float* cur1 = (float*)ws;
  size_t off = (size_t)M * 128 * 4;
  ushort* w1h = (ushort*)(ws + off); off += 128 * 704 * 2;
  ushort* w1l = (ushort*)(ws + off); off += 128 * 704 * 2;
  ushort* w2h = (ushort*)(ws + off); off += 256 * 128 * 2;
  ushort* w2l = (ushort*)(ws + off); off += 256 * 128 * 2;
  ushort* w3h = (ushort*)(ws + off); off += 32 * 256 * 2;
  ushort* w3l = (ushort*)(ws + off); off += 32 * 256 * 2;

  split_w_all_kernel<<<512, 256, 0, stream>>>(W1, w1h, w1l, W2, w2h, w2l, W3, w3h, w3l);

  gemm1_kernel<<<M / 64, 512, 0, stream>>>(x, w1h, w1l, cur1);
  fused_l23_kernel<<<256, 512, 0, stream>>>(cur1, b1, w2h, w2l, b2, w3h, w3l, b3,
                                            beta1, beta2, beta3, thr1, thr2, thr3, out);
}

// Round 18
// 183.858 us; speedup vs baseline: 1.1652x; 1.1652x over previous
//
#include <hip/hip_runtime.h>

typedef __attribute__((ext_vector_type(8))) short short8;
typedef __attribute__((ext_vector_type(4))) float f32x4;

#define MFMA16(a, b, c) __builtin_amdgcn_mfma_f32_16x16x32_bf16(a, b, c, 0, 0, 0)

__device__ __forceinline__ ushort bf16_rne(float f) {
  uint u = __float_as_uint(f);
  u += 0x7FFFu + ((u >> 16) & 1u);
  return (ushort)(u >> 16);
}

__device__ __forceinline__ void gload_lds16(const void* g, void* l) {
  __builtin_amdgcn_global_load_lds((const __attribute__((address_space(1))) uint*)g,
                                   (__attribute__((address_space(3))) uint*)l, 16, 0, 0);
}

// ---------------- merged weight split (3 tensors, one launch) ----------------
__global__ void split_w_all_kernel(const float* __restrict__ W1, ushort* __restrict__ w1h,
                                   ushort* __restrict__ w1l, const float* __restrict__ W2,
                                   ushort* __restrict__ w2h, ushort* __restrict__ w2l,
                                   const float* __restrict__ W3, ushort* __restrict__ w3h,
                                   ushort* __restrict__ w3l) {
  int i = blockIdx.x * 256 + threadIdx.x;
  const float* W;
  ushort *hi, *lo;
  int Nr, K, Kp;
  if (i < 128 * 704) {
    W = W1; hi = w1h; lo = w1l; Nr = 128; K = 700; Kp = 704;
  } else if (i < 128 * 704 + 256 * 128) {
    i -= 128 * 704;
    W = W2; hi = w2h; lo = w2l; Nr = 256; K = 128; Kp = 128;
  } else {
    i -= 128 * 704 + 256 * 128;
    W = W3; hi = w3h; lo = w3l; Nr = 20; K = 256; Kp = 256;
  }
  int r = i / Kp, k = i - r * Kp;
  float v = (r < Nr && k < K) ? W[(size_t)r * K + k] : 0.f;
  ushort h = bf16_rne(v);
  float hf = __uint_as_float(((uint)h) << 16);
  ushort l = bf16_rne(v - hf);
  hi[i] = h;
  lo[i] = l;
}

// ---------------- GEMM1 v4 (best measured): cur1 = x @ W1^T, 3-pass split-bf16 ----
// M-tile 64 (grid 2000), 48 KB LDS -> 3 blocks/CU. B staged via global_load_lds
// (linear LDS dest, pre-swizzled global source). A reg-prefetched + packed convert.
// Plain __syncthreads. Measured ceiling of this structure; all schedule surgery
// (counted vmcnt, dbuf, barrier-free, deeper prefetch) measured null or negative.
__global__ __launch_bounds__(256, 3) void gemm1_kernel(const float* __restrict__ A,
                                                       const ushort* __restrict__ Bh,
                                                       const ushort* __restrict__ Bl,
                                                       float* __restrict__ C) {
  __shared__ ushort sAh[64 * 64];
  __shared__ ushort sAl[64 * 64];
  __shared__ ushort sBh[128 * 64];
  __shared__ ushort sBl[128 * 64];

  const int tid = threadIdx.x;
  const int lane = tid & 63;
  const int wid = tid >> 6;
  const int tr = tid >> 2, tg = tid & 3;
  const int wr = wid >> 1, wc = wid & 1;
  const int m0 = blockIdx.x * 64;

  const int brow_lo = lane >> 3;
  const int bswz = (((lane & 7) ^ brow_lo) << 3);
  const size_t bgoff = (size_t)(wid * 32 + brow_lo) * 704 + bswz;

  f32x4 acc[2][4];
#pragma unroll
  for (int i = 0; i < 2; ++i)
#pragma unroll
    for (int j = 0; j < 4; ++j) acc[i][j] = f32x4{0.f, 0.f, 0.f, 0.f};

  float4 pf[4];
  auto load_a = [&](int ks) {
    const float* ap = A + (size_t)(m0 + tr) * 700 + ks * 64 + tg * 16;
#pragma unroll
    for (int q = 0; q < 4; ++q) {
      float4 z;
      z.x = z.y = z.z = z.w = 0.f;
      pf[q] = (ks * 64 + tg * 16 + q * 4 + 3 < 700) ? *(const float4*)(ap + q * 4) : z;
    }
  };
  load_a(0);

  for (int ks = 0; ks < 11; ++ks) {
    // ---- B: direct global->LDS (no VGPR); latency covered by A convert below ----
#pragma unroll
    for (int p = 0; p < 4; ++p) {
      const size_t go = bgoff + (size_t)p * 8 * 704 + ks * 64;
      gload_lds16(Bh + go, &sBh[(wid * 32 + p * 8) * 64]);
      gload_lds16(Bl + go, &sBl[(wid * 32 + p * 8) * 64]);
    }
    // ---- A: packed convert of 16 prefetched elems -> LDS (2 swizzled 8-groups) ----
#pragma unroll
    for (int h = 0; h < 2; ++h) {
      const float* vf = (const float*)&pf[h * 2];
      uint hw[4], lw[4];
#pragma unroll
      for (int q = 0; q < 4; ++q) {
        const uint u0 = __float_as_uint(vf[2 * q]);
        const uint u1 = __float_as_uint(vf[2 * q + 1]);
        hw[q] = __builtin_amdgcn_perm(u1, u0, 0x07060302u);  // {u0.hi16, u1.hi16}
        const float d0 = vf[2 * q] - __uint_as_float(u0 & 0xFFFF0000u);
        const float d1 = vf[2 * q + 1] - __uint_as_float(u1 & 0xFFFF0000u);
        asm("v_cvt_pk_bf16_f32 %0, %1, %2" : "=v"(lw[q]) : "v"(d0), "v"(d1));
      }
      const int off = tr * 64 + (((tg * 2 + h) ^ (tr & 7)) << 3);
      uint4 qh, ql;
      qh.x = hw[0]; qh.y = hw[1]; qh.z = hw[2]; qh.w = hw[3];
      ql.x = lw[0]; ql.y = lw[1]; ql.z = lw[2]; ql.w = lw[3];
      *(uint4*)&sAh[off] = qh;
      *(uint4*)&sAl[off] = ql;
    }
    __syncthreads();
    if (ks < 10) load_a(ks + 1);  // flies under MFMA phase

#pragma unroll
    for (int ku = 0; ku < 2; ++ku) {
      const int g0 = ku * 4 + (lane >> 4);
      short8 ah[2], al[2];
#pragma unroll
      for (int i = 0; i < 2; ++i) {
        const int r = wr * 32 + i * 16 + (lane & 15);
        const int off = r * 64 + ((g0 ^ (r & 7)) << 3);
        ah[i] = *(const short8*)&sAh[off];
        al[i] = *(const short8*)&sAl[off];
      }
      short8 bh[4], bl[4];
#pragma unroll
      for (int j = 0; j < 4; ++j) {
        const int r = wc * 64 + j * 16 + (lane & 15);
        const int off = r * 64 + ((g0 ^ (r & 7)) << 3);
        bh[j] = *(const short8*)&sBh[off];
        bl[j] = *(const short8*)&sBl[off];
      }
#pragma unroll
      for (int i = 0; i < 2; ++i)
#pragma unroll
        for (int j = 0; j < 4; ++j) {
          acc[i][j] = MFMA16(ah[i], bh[j], acc[i][j]);
          acc[i][j] = MFMA16(al[i], bh[j], acc[i][j]);
          acc[i][j] = MFMA16(ah[i], bl[j], acc[i][j]);
        }
    }
    __syncthreads();
  }

#pragma unroll
  for (int i = 0; i < 2; ++i) {
    const int rbase = m0 + wr * 32 + i * 16 + ((lane >> 4) << 2);
#pragma unroll
    for (int j = 0; j < 4; ++j) {
      const int col = wc * 64 + j * 16 + (lane & 15);
#pragma unroll
      for (int rg = 0; rg < 4; ++rg)
        C[(size_t)(rbase + rg) * 128 + col] = acc[i][j][rg];
    }
  }
}

// ---------------- fused layers 2+3 v4 (best measured): W2 in registers ----------------
__global__ __launch_bounds__(512, 2) void fused_l23_kernel(
    const float* __restrict__ cur1, const float* __restrict__ b1,
    const ushort* __restrict__ w2h, const ushort* __restrict__ w2l, const float* __restrict__ b2,
    const ushort* __restrict__ w3h, const ushort* __restrict__ w3l, const float* __restrict__ b3,
    const float* __restrict__ beta1p, const float* __restrict__ beta2p,
    const float* __restrict__ beta3p, const float* __restrict__ thr1p,
    const float* __restrict__ thr2p, const float* __restrict__ thr3p,
    float* __restrict__ out) {
  __shared__ __align__(16) char smem[156672];
  float* buf = (float*)smem;
  ushort* s1 = (ushort*)(smem + 32768);
  float* c2 = (float*)(smem + 49152);
  ushort* s2 = (ushort*)(smem + 49152);
  ushort* w3p = (ushort*)(smem + 114688);
  float* c3 = (float*)(smem + 147456);

  const int tid = threadIdx.x;
  const int lane = tid & 63;
  const int w = tid >> 6;
  const int b = blockIdx.x;
  const int lr = lane & 15, lg = lane >> 4;

  const float be1 = fminf(fmaxf(beta1p[0], 0.f), 1.f), th1 = thr1p[0];
  const float be2 = fminf(fmaxf(beta2p[0], 0.f), 1.f), th2 = thr2p[0];
  const float be3 = fminf(fmaxf(beta3p[0], 0.f), 1.f), th3 = thr3p[0];
  const float bi1 = (tid < 128) ? b1[tid] : 0.f;
  const float bi2 = (tid < 256) ? b2[tid] : 0.f;
  const float bi3 = (tid >= 128 && tid < 148) ? b3[tid - 128] : 0.f;

  short8 w2fh[2][4], w2fl[2][4];
#pragma unroll
  for (int j = 0; j < 2; ++j)
#pragma unroll
    for (int ks = 0; ks < 4; ++ks) {
      const size_t o = (size_t)(w * 32 + j * 16 + lr) * 128 + ks * 32 + lg * 8;
      w2fh[j][ks] = *(const short8*)(w2h + o);
      w2fl[j][ks] = *(const short8*)(w2l + o);
    }
#pragma unroll
  for (int p = 0; p < 2; ++p) {
    const int r = p * 16 + (tid >> 5);
    const int g = tid & 31;
    const int swz = ((g ^ (r & 7)) << 3);
    *(uint4*)&w3p[r * 256 + g * 8] = *(const uint4*)(w3h + r * 256 + swz);
    *(uint4*)&w3p[8192 + r * 256 + g * 8] = *(const uint4*)(w3l + r * 256 + swz);
  }
  const float4* cg4 = (const float4*)cur1 + (size_t)b * 16000;
#pragma unroll
  for (int i = 0; i < 4; ++i) ((float4*)buf)[i * 512 + tid] = cg4[i * 512 + tid];
  __syncthreads();

  float m1 = 0.f, m2 = 0.f, m3 = 0.f, a3 = 0.f;

  for (int c = 0; c < 8; ++c) {
    const int t0 = c * 64;

    // ---- P1: LIF1(c) on tid<128  ||  LIF3(c-1) on tid 128..147 ----
    if (tid < 128) {
      const int g = tid >> 3, nb = tid & 7;
#pragma unroll
      for (int hh = 0; hh < 2; ++hh) {
        float v[32];
#pragma unroll
        for (int u = 0; u < 32; ++u) v[u] = buf[(hh * 32 + u) * 128 + tid];
#pragma unroll
        for (int u = 0; u < 32; ++u) {
          const int row = hh * 32 + u;
          const int t = t0 + row;
          ushort sp = 0;
          if (t < 500) {
            float r = (m1 > th1) ? th1 : 0.f;
            m1 = be1 * m1 + (v[u] + bi1) - r;
            sp = (m1 > th1) ? (ushort)0x3F80 : (ushort)0;
          }
          s1[row * 128 + ((g ^ (row & 7)) << 3) + nb] = sp;
        }
      }
    } else if (tid < 148 && c > 0) {
      const int n = tid - 128;
      const int tp = (c - 1) * 64;
#pragma unroll 8
      for (int u = 0; u < 64; ++u) {
        if (tp + u < 500) {
          const float v = c3[u * 36 + n];
          float r = (m3 > th3) ? th3 : 0.f;
          m3 = be3 * m3 + (v + bi3) - r;
          a3 += (m3 > th3) ? 1.f : 0.f;
        }
      }
    }
    __syncthreads();

    // ---- P2: G2 from registers: c2[64][256] = s1 @ W2^T ----
    {
      f32x4 acc[4][2];
#pragma unroll
      for (int i = 0; i < 4; ++i)
#pragma unroll
        for (int j = 0; j < 2; ++j) acc[i][j] = f32x4{0.f, 0.f, 0.f, 0.f};
#pragma unroll
      for (int ks = 0; ks < 4; ++ks) {
        const int G = ks * 4 + lg;
        short8 ah[4];
#pragma unroll
        for (int i = 0; i < 4; ++i) {
          const int r = i * 16 + lr;
          ah[i] = *(const short8*)&s1[r * 128 + ((G ^ (r & 7)) << 3)];
        }
#pragma unroll
        for (int j = 0; j < 2; ++j)
#pragma unroll
          for (int i = 0; i < 4; ++i) {
            acc[i][j] = MFMA16(ah[i], w2fh[j][ks], acc[i][j]);
            acc[i][j] = MFMA16(ah[i], w2fl[j][ks], acc[i][j]);
          }
      }
#pragma unroll
      for (int i = 0; i < 4; ++i) {
        const int rbase = i * 16 + (lg << 2);
#pragma unroll
        for (int j = 0; j < 2; ++j) {
          const int col = w * 32 + j * 16 + lr;
#pragma unroll
          for (int rg = 0; rg < 4; ++rg) {
            const int row = rbase + rg;
            c2[row * 256 + (col ^ ((row & 7) << 2))] = acc[i][j][rg];
          }
        }
      }
    }
    __syncthreads();

    // ---- P3: read c2 rows 0..31 (tid<256)  ||  buf(c+1) HBM prefetch (tid>=256) ----
    float v[32];
    if (tid < 256) {
#pragma unroll
      for (int u = 0; u < 32; ++u) v[u] = c2[u * 256 + (tid ^ ((u & 7) << 2))];
    } else if (c < 7) {
      const int base = (c + 1) * 2048;
#pragma unroll
      for (int i = 0; i < 8; ++i)
        ((float4*)buf)[i * 256 + (tid - 256)] = cg4[base + i * 256 + (tid - 256)];
    }
    __syncthreads();

    // ---- P4: LIF2 ----
    if (tid < 256) {
      const int g = tid >> 3, nb = tid & 7;
#pragma unroll
      for (int u = 0; u < 32; ++u) {
        const int t = t0 + u;
        ushort sp = 0;
        if (t < 500) {
          float r = (m2 > th2) ? th2 : 0.f;
          m2 = be2 * m2 + (v[u] + bi2) - r;
          sp = (m2 > th2) ? (ushort)0x3F80 : (ushort)0;
        }
        s2[u * 256 + ((g ^ (u & 7)) << 3) + nb] = sp;
      }
#pragma unroll
      for (int u = 0; u < 32; ++u) v[u] = c2[(32 + u) * 256 + (tid ^ ((u & 7) << 2))];
#pragma unroll
      for (int u = 0; u < 32; ++u) {
        const int row = 32 + u;
        const int t = t0 + row;
        ushort sp = 0;
        if (t < 500) {
          float r = (m2 > th2) ? th2 : 0.f;
          m2 = be2 * m2 + (v[u] + bi2) - r;
          sp = (m2 > th2) ? (ushort)0x3F80 : (ushort)0;
        }
        s2[row * 256 + ((g ^ (row & 7)) << 3) + nb] = sp;
      }
    }
    __syncthreads();

    // ---- P5: G3: c3[64][32] = s2 @ W3^T ----
    {
      const int wr3 = w >> 1, wc3 = w & 1;
      f32x4 a3c = f32x4{0.f, 0.f, 0.f, 0.f};
#pragma unroll
      for (int ku = 0; ku < 8; ++ku) {
        const int G = ku * 4 + lg;
        const int rb = wc3 * 16 + lr;
        const int ob = rb * 256 + ((G ^ (rb & 7)) << 3);
        short8 vbh = *(const short8*)&w3p[ob];
        short8 vbl = *(const short8*)&w3p[8192 + ob];
        const int r = wr3 * 16 + lr;
        short8 av = *(const short8*)&s2[r * 256 + ((G ^ (r & 7)) << 3)];
        a3c = MFMA16(av, vbh, a3c);
        a3c = MFMA16(av, vbl, a3c);
      }
      const int rb3 = wr3 * 16 + (lg << 2);
      const int col3 = wc3 * 16 + lr;
#pragma unroll
      for (int rg = 0; rg < 4; ++rg) c3[(rb3 + rg) * 36 + col3] = a3c[rg];
    }
    __syncthreads();
  }

  if (tid >= 128 && tid < 148) {
    const int n = tid - 128;
#pragma unroll 8
    for (int u = 0; u < 64; ++u) {
      if (448 + u < 500) {
        const float v = c3[u * 36 + n];
        float r = (m3 > th3) ? th3 : 0.f;
        m3 = be3 * m3 + (v + bi3) - r;
        a3 += (m3 > th3) ? 1.f : 0.f;
      }
    }
    out[(size_t)b * 20 + n] = a3 * (1.f / 500.f);
  }
}

extern "C" void kernel_launch(void* const* d_in, const int* in_sizes, int n_in, void* d_out,
                              int out_size, void* d_ws, size_t ws_size, hipStream_t stream) {
  const float* x = (const float*)d_in[0];
  const float* W1 = (const float*)d_in[1];
  const float* b1 = (const float*)d_in[2];
  const float* W2 = (const float*)d_in[3];
  const float* b2 = (const float*)d_in[4];
  const float* W3 = (const float*)d_in[5];
  const float* b3 = (const float*)d_in[6];
  const float* beta1 = (const float*)d_in[7];
  const float* beta2 = (const float*)d_in[8];
  const float* beta3 = (const float*)d_in[9];
  const float* thr1 = (const float*)d_in[10];
  const float* thr2 = (const float*)d_in[11];
  const float* thr3 = (const float*)d_in[12];
  float* out = (float*)d_out;

  const int M = 128000;  // B*T
  char* ws = (char*)d_ws;
  float* cur1 = (float*)ws;
  size_t off = (size_t)M * 128 * 4;
  ushort* w1h = (ushort*)(ws + off); off += 128 * 704 * 2;
  ushort* w1l = (ushort*)(ws + off); off += 128 * 704 * 2;
  ushort* w2h = (ushort*)(ws + off); off += 256 * 128 * 2;
  ushort* w2l = (ushort*)(ws + off); off += 256 * 128 * 2;
  ushort* w3h = (ushort*)(ws + off); off += 32 * 256 * 2;
  ushort* w3l = (ushort*)(ws + off); off += 32 * 256 * 2;

  split_w_all_kernel<<<512, 256, 0, stream>>>(W1, w1h, w1l, W2, w2h, w2l, W3, w3h, w3l);

  gemm1_kernel<<<M / 64, 256, 0, stream>>>(x, w1h, w1l, cur1);
  fused_l23_kernel<<<256, 512, 0, stream>>>(cur1, b1, w2h, w2l, b2, w3h, w3l, b3,
                                            beta1, beta2, beta3, thr1, thr2, thr3, out);
}

// Round 19
// 183.682 us; speedup vs baseline: 1.1663x; 1.0010x over previous
//
#include <hip/hip_runtime.h>

typedef __attribute__((ext_vector_type(8))) short short8;
typedef __attribute__((ext_vector_type(4))) float f32x4;

#define MFMA16(a, b, c) __builtin_amdgcn_mfma_f32_16x16x32_bf16(a, b, c, 0, 0, 0)

__device__ __forceinline__ ushort bf16_rne(float f) {
  uint u = __float_as_uint(f);
  u += 0x7FFFu + ((u >> 16) & 1u);
  return (ushort)(u >> 16);
}

__device__ __forceinline__ void gload_lds16(const void* g, void* l) {
  __builtin_amdgcn_global_load_lds((const __attribute__((address_space(1))) uint*)g,
                                   (__attribute__((address_space(3))) uint*)l, 16, 0, 0);
}

// ---------------- merged weight split (3 tensors, one launch) ----------------
__global__ void split_w_all_kernel(const float* __restrict__ W1, ushort* __restrict__ w1h,
                                   ushort* __restrict__ w1l, const float* __restrict__ W2,
                                   ushort* __restrict__ w2h, ushort* __restrict__ w2l,
                                   const float* __restrict__ W3, ushort* __restrict__ w3h,
                                   ushort* __restrict__ w3l) {
  int i = blockIdx.x * 256 + threadIdx.x;
  const float* W;
  ushort *hi, *lo;
  int Nr, K, Kp;
  if (i < 128 * 704) {
    W = W1; hi = w1h; lo = w1l; Nr = 128; K = 700; Kp = 704;
  } else if (i < 128 * 704 + 256 * 128) {
    i -= 128 * 704;
    W = W2; hi = w2h; lo = w2l; Nr = 256; K = 128; Kp = 128;
  } else {
    i -= 128 * 704 + 256 * 128;
    W = W3; hi = w3h; lo = w3l; Nr = 20; K = 256; Kp = 256;
  }
  int r = i / Kp, k = i - r * Kp;
  float v = (r < Nr && k < K) ? W[(size_t)r * K + k] : 0.f;
  ushort h = bf16_rne(v);
  float hf = __uint_as_float(((uint)h) << 16);
  ushort l = bf16_rne(v - hf);
  hi[i] = h;
  lo[i] = l;
}

// ---------------- GEMM1 v4 (terminal): cur1 = x @ W1^T, 3-pass split-bf16 ----
// M-tile 64 (grid 2000), 48 KB LDS -> 3 blocks/CU. B staged via global_load_lds
// (linear LDS dest, pre-swizzled global source). A reg-prefetched + packed convert.
// Plain __syncthreads. Structural ceiling of this 2-barrier shape: 8 schedule
// interventions measured null/negative (see session journal R7-R17).
__global__ __launch_bounds__(256, 3) void gemm1_kernel(const float* __restrict__ A,
                                                       const ushort* __restrict__ Bh,
                                                       const ushort* __restrict__ Bl,
                                                       float* __restrict__ C) {
  __shared__ ushort sAh[64 * 64];
  __shared__ ushort sAl[64 * 64];
  __shared__ ushort sBh[128 * 64];
  __shared__ ushort sBl[128 * 64];

  const int tid = threadIdx.x;
  const int lane = tid & 63;
  const int wid = tid >> 6;
  const int tr = tid >> 2, tg = tid & 3;
  const int wr = wid >> 1, wc = wid & 1;
  const int m0 = blockIdx.x * 64;

  const int brow_lo = lane >> 3;
  const int bswz = (((lane & 7) ^ brow_lo) << 3);
  const size_t bgoff = (size_t)(wid * 32 + brow_lo) * 704 + bswz;

  f32x4 acc[2][4];
#pragma unroll
  for (int i = 0; i < 2; ++i)
#pragma unroll
    for (int j = 0; j < 4; ++j) acc[i][j] = f32x4{0.f, 0.f, 0.f, 0.f};

  float4 pf[4];
  auto load_a = [&](int ks) {
    const float* ap = A + (size_t)(m0 + tr) * 700 + ks * 64 + tg * 16;
#pragma unroll
    for (int q = 0; q < 4; ++q) {
      float4 z;
      z.x = z.y = z.z = z.w = 0.f;
      pf[q] = (ks * 64 + tg * 16 + q * 4 + 3 < 700) ? *(const float4*)(ap + q * 4) : z;
    }
  };
  load_a(0);

  for (int ks = 0; ks < 11; ++ks) {
    // ---- B: direct global->LDS (no VGPR); latency covered by A convert below ----
#pragma unroll
    for (int p = 0; p < 4; ++p) {
      const size_t go = bgoff + (size_t)p * 8 * 704 + ks * 64;
      gload_lds16(Bh + go, &sBh[(wid * 32 + p * 8) * 64]);
      gload_lds16(Bl + go, &sBl[(wid * 32 + p * 8) * 64]);
    }
    // ---- A: packed convert of 16 prefetched elems -> LDS (2 swizzled 8-groups) ----
#pragma unroll
    for (int h = 0; h < 2; ++h) {
      const float* vf = (const float*)&pf[h * 2];
      uint hw[4], lw[4];
#pragma unroll
      for (int q = 0; q < 4; ++q) {
        const uint u0 = __float_as_uint(vf[2 * q]);
        const uint u1 = __float_as_uint(vf[2 * q + 1]);
        hw[q] = __builtin_amdgcn_perm(u1, u0, 0x07060302u);  // {u0.hi16, u1.hi16}
        const float d0 = vf[2 * q] - __uint_as_float(u0 & 0xFFFF0000u);
        const float d1 = vf[2 * q + 1] - __uint_as_float(u1 & 0xFFFF0000u);
        asm("v_cvt_pk_bf16_f32 %0, %1, %2" : "=v"(lw[q]) : "v"(d0), "v"(d1));
      }
      const int off = tr * 64 + (((tg * 2 + h) ^ (tr & 7)) << 3);
      uint4 qh, ql;
      qh.x = hw[0]; qh.y = hw[1]; qh.z = hw[2]; qh.w = hw[3];
      ql.x = lw[0]; ql.y = lw[1]; ql.z = lw[2]; ql.w = lw[3];
      *(uint4*)&sAh[off] = qh;
      *(uint4*)&sAl[off] = ql;
    }
    __syncthreads();
    if (ks < 10) load_a(ks + 1);  // flies under MFMA phase

#pragma unroll
    for (int ku = 0; ku < 2; ++ku) {
      const int g0 = ku * 4 + (lane >> 4);
      short8 ah[2], al[2];
#pragma unroll
      for (int i = 0; i < 2; ++i) {
        const int r = wr * 32 + i * 16 + (lane & 15);
        const int off = r * 64 + ((g0 ^ (r & 7)) << 3);
        ah[i] = *(const short8*)&sAh[off];
        al[i] = *(const short8*)&sAl[off];
      }
      short8 bh[4], bl[4];
#pragma unroll
      for (int j = 0; j < 4; ++j) {
        const int r = wc * 64 + j * 16 + (lane & 15);
        const int off = r * 64 + ((g0 ^ (r & 7)) << 3);
        bh[j] = *(const short8*)&sBh[off];
        bl[j] = *(const short8*)&sBl[off];
      }
#pragma unroll
      for (int i = 0; i < 2; ++i)
#pragma unroll
        for (int j = 0; j < 4; ++j) {
          acc[i][j] = MFMA16(ah[i], bh[j], acc[i][j]);
          acc[i][j] = MFMA16(al[i], bh[j], acc[i][j]);
          acc[i][j] = MFMA16(ah[i], bl[j], acc[i][j]);
        }
    }
    __syncthreads();
  }

#pragma unroll
  for (int i = 0; i < 2; ++i) {
    const int rbase = m0 + wr * 32 + i * 16 + ((lane >> 4) << 2);
#pragma unroll
    for (int j = 0; j < 4; ++j) {
      const int col = wc * 64 + j * 16 + (lane & 15);
#pragma unroll
      for (int rg = 0; rg < 4; ++rg)
        C[(size_t)(rbase + rg) * 128 + col] = acc[i][j][rg];
    }
  }
}

// ---------------- fused layers 2+3 v4 (terminal): W2 in registers ----------------
__global__ __launch_bounds__(512, 2) void fused_l23_kernel(
    const float* __restrict__ cur1, const float* __restrict__ b1,
    const ushort* __restrict__ w2h, const ushort* __restrict__ w2l, const float* __restrict__ b2,
    const ushort* __restrict__ w3h, const ushort* __restrict__ w3l, const float* __restrict__ b3,
    const float* __restrict__ beta1p, const float* __restrict__ beta2p,
    const float* __restrict__ beta3p, const float* __restrict__ thr1p,
    const float* __restrict__ thr2p, const float* __restrict__ thr3p,
    float* __restrict__ out) {
  __shared__ __align__(16) char smem[156672];
  float* buf = (float*)smem;
  ushort* s1 = (ushort*)(smem + 32768);
  float* c2 = (float*)(smem + 49152);
  ushort* s2 = (ushort*)(smem + 49152);
  ushort* w3p = (ushort*)(smem + 114688);
  float* c3 = (float*)(smem + 147456);

  const int tid = threadIdx.x;
  const int lane = tid & 63;
  const int w = tid >> 6;
  const int b = blockIdx.x;
  const int lr = lane & 15, lg = lane >> 4;

  const float be1 = fminf(fmaxf(beta1p[0], 0.f), 1.f), th1 = thr1p[0];
  const float be2 = fminf(fmaxf(beta2p[0], 0.f), 1.f), th2 = thr2p[0];
  const float be3 = fminf(fmaxf(beta3p[0], 0.f), 1.f), th3 = thr3p[0];
  const float bi1 = (tid < 128) ? b1[tid] : 0.f;
  const float bi2 = (tid < 256) ? b2[tid] : 0.f;
  const float bi3 = (tid >= 128 && tid < 148) ? b3[tid - 128] : 0.f;

  short8 w2fh[2][4], w2fl[2][4];
#pragma unroll
  for (int j = 0; j < 2; ++j)
#pragma unroll
    for (int ks = 0; ks < 4; ++ks) {
      const size_t o = (size_t)(w * 32 + j * 16 + lr) * 128 + ks * 32 + lg * 8;
      w2fh[j][ks] = *(const short8*)(w2h + o);
      w2fl[j][ks] = *(const short8*)(w2l + o);
    }
#pragma unroll
  for (int p = 0; p < 2; ++p) {
    const int r = p * 16 + (tid >> 5);
    const int g = tid & 31;
    const int swz = ((g ^ (r & 7)) << 3);
    *(uint4*)&w3p[r * 256 + g * 8] = *(const uint4*)(w3h + r * 256 + swz);
    *(uint4*)&w3p[8192 + r * 256 + g * 8] = *(const uint4*)(w3l + r * 256 + swz);
  }
  const float4* cg4 = (const float4*)cur1 + (size_t)b * 16000;
#pragma unroll
  for (int i = 0; i < 4; ++i) ((float4*)buf)[i * 512 + tid] = cg4[i * 512 + tid];
  __syncthreads();

  float m1 = 0.f, m2 = 0.f, m3 = 0.f, a3 = 0.f;

  for (int c = 0; c < 8; ++c) {
    const int t0 = c * 64;

    // ---- P1: LIF1(c) on tid<128  ||  LIF3(c-1) on tid 128..147 ----
    if (tid < 128) {
      const int g = tid >> 3, nb = tid & 7;
#pragma unroll
      for (int hh = 0; hh < 2; ++hh) {
        float v[32];
#pragma unroll
        for (int u = 0; u < 32; ++u) v[u] = buf[(hh * 32 + u) * 128 + tid];
#pragma unroll
        for (int u = 0; u < 32; ++u) {
          const int row = hh * 32 + u;
          const int t = t0 + row;
          ushort sp = 0;
          if (t < 500) {
            float r = (m1 > th1) ? th1 : 0.f;
            m1 = be1 * m1 + (v[u] + bi1) - r;
            sp = (m1 > th1) ? (ushort)0x3F80 : (ushort)0;
          }
          s1[row * 128 + ((g ^ (row & 7)) << 3) + nb] = sp;
        }
      }
    } else if (tid < 148 && c > 0) {
      const int n = tid - 128;
      const int tp = (c - 1) * 64;
#pragma unroll 8
      for (int u = 0; u < 64; ++u) {
        if (tp + u < 500) {
          const float v = c3[u * 36 + n];
          float r = (m3 > th3) ? th3 : 0.f;
          m3 = be3 * m3 + (v + bi3) - r;
          a3 += (m3 > th3) ? 1.f : 0.f;
        }
      }
    }
    __syncthreads();

    // ---- P2: G2 from registers: c2[64][256] = s1 @ W2^T ----
    {
      f32x4 acc[4][2];
#pragma unroll
      for (int i = 0; i < 4; ++i)
#pragma unroll
        for (int j = 0; j < 2; ++j) acc[i][j] = f32x4{0.f, 0.f, 0.f, 0.f};
#pragma unroll
      for (int ks = 0; ks < 4; ++ks) {
        const int G = ks * 4 + lg;
        short8 ah[4];
#pragma unroll
        for (int i = 0; i < 4; ++i) {
          const int r = i * 16 + lr;
          ah[i] = *(const short8*)&s1[r * 128 + ((G ^ (r & 7)) << 3)];
        }
#pragma unroll
        for (int j = 0; j < 2; ++j)
#pragma unroll
          for (int i = 0; i < 4; ++i) {
            acc[i][j] = MFMA16(ah[i], w2fh[j][ks], acc[i][j]);
            acc[i][j] = MFMA16(ah[i], w2fl[j][ks], acc[i][j]);
          }
      }
#pragma unroll
      for (int i = 0; i < 4; ++i) {
        const int rbase = i * 16 + (lg << 2);
#pragma unroll
        for (int j = 0; j < 2; ++j) {
          const int col = w * 32 + j * 16 + lr;
#pragma unroll
          for (int rg = 0; rg < 4; ++rg) {
            const int row = rbase + rg;
            c2[row * 256 + (col ^ ((row & 7) << 2))] = acc[i][j][rg];
          }
        }
      }
    }
    __syncthreads();

    // ---- P3: read c2 rows 0..31 (tid<256)  ||  buf(c+1) HBM prefetch (tid>=256) ----
    float v[32];
    if (tid < 256) {
#pragma unroll
      for (int u = 0; u < 32; ++u) v[u] = c2[u * 256 + (tid ^ ((u & 7) << 2))];
    } else if (c < 7) {
      const int base = (c + 1) * 2048;
#pragma unroll
      for (int i = 0; i < 8; ++i)
        ((float4*)buf)[i * 256 + (tid - 256)] = cg4[base + i * 256 + (tid - 256)];
    }
    __syncthreads();

    // ---- P4: LIF2 ----
    if (tid < 256) {
      const int g = tid >> 3, nb = tid & 7;
#pragma unroll
      for (int u = 0; u < 32; ++u) {
        const int t = t0 + u;
        ushort sp = 0;
        if (t < 500) {
          float r = (m2 > th2) ? th2 : 0.f;
          m2 = be2 * m2 + (v[u] + bi2) - r;
          sp = (m2 > th2) ? (ushort)0x3F80 : (ushort)0;
        }
        s2[u * 256 + ((g ^ (u & 7)) << 3) + nb] = sp;
      }
#pragma unroll
      for (int u = 0; u < 32; ++u) v[u] = c2[(32 + u) * 256 + (tid ^ ((u & 7) << 2))];
#pragma unroll
      for (int u = 0; u < 32; ++u) {
        const int row = 32 + u;
        const int t = t0 + row;
        ushort sp = 0;
        if (t < 500) {
          float r = (m2 > th2) ? th2 : 0.f;
          m2 = be2 * m2 + (v[u] + bi2) - r;
          sp = (m2 > th2) ? (ushort)0x3F80 : (ushort)0;
        }
        s2[row * 256 + ((g ^ (row & 7)) << 3) + nb] = sp;
      }
    }
    __syncthreads();

    // ---- P5: G3: c3[64][32] = s2 @ W3^T ----
    {
      const int wr3 = w >> 1, wc3 = w & 1;
      f32x4 a3c = f32x4{0.f, 0.f, 0.f, 0.f};
#pragma unroll
      for (int ku = 0; ku < 8; ++ku) {
        const int G = ku * 4 + lg;
        const int rb = wc3 * 16 + lr;
        const int ob = rb * 256 + ((G ^ (rb & 7)) << 3);
        short8 vbh = *(const short8*)&w3p[ob];
        short8 vbl = *(const short8*)&w3p[8192 + ob];
        const int r = wr3 * 16 + lr;
        short8 av = *(const short8*)&s2[r * 256 + ((G ^ (r & 7)) << 3)];
        a3c = MFMA16(av, vbh, a3c);
        a3c = MFMA16(av, vbl, a3c);
      }
      const int rb3 = wr3 * 16 + (lg << 2);
      const int col3 = wc3 * 16 + lr;
#pragma unroll
      for (int rg = 0; rg < 4; ++rg) c3[(rb3 + rg) * 36 + col3] = a3c[rg];
    }
    __syncthreads();
  }

  if (tid >= 128 && tid < 148) {
    const int n = tid - 128;
#pragma unroll 8
    for (int u = 0; u < 64; ++u) {
      if (448 + u < 500) {
        const float v = c3[u * 36 + n];
        float r = (m3 > th3) ? th3 : 0.f;
        m3 = be3 * m3 + (v + bi3) - r;
        a3 += (m3 > th3) ? 1.f : 0.f;
      }
    }
    out[(size_t)b * 20 + n] = a3 * (1.f / 500.f);
  }
}

extern "C" void kernel_launch(void* const* d_in, const int* in_sizes, int n_in, void* d_out,
                              int out_size, void* d_ws, size_t ws_size, hipStream_t stream) {
  const float* x = (const float*)d_in[0];
  const float* W1 = (const float*)d_in[1];
  const float* b1 = (const float*)d_in[2];
  const float* W2 = (const float*)d_in[3];
  const float* b2 = (const float*)d_in[4];
  const float* W3 = (const float*)d_in[5];
  const float* b3 = (const float*)d_in[6];
  const float* beta1 = (const float*)d_in[7];
  const float* beta2 = (const float*)d_in[8];
  const float* beta3 = (const float*)d_in[9];
  const float* thr1 = (const float*)d_in[10];
  const float* thr2 = (const float*)d_in[11];
  const float* thr3 = (const float*)d_in[12];
  float* out = (float*)d_out;

  const int M = 128000;  // B*T
  char* ws = (char*)d_ws;
  float* cur1 = (float*)ws;
  size_t off = (size_t)M * 128 * 4;
  ushort* w1h = (ushort*)(ws + off); off += 128 * 704 * 2;
  ushort* w1l = (ushort*)(ws + off); off += 128 * 704 * 2;
  ushort* w2h = (ushort*)(ws + off); off += 256 * 128 * 2;
  ushort* w2l = (ushort*)(ws + off); off += 256 * 128 * 2;
  ushort* w3h = (ushort*)(ws + off); off += 32 * 256 * 2;
  ushort* w3l = (ushort*)(ws + off); off += 32 * 256 * 2;

  split_w_all_kernel<<<512, 256, 0, stream>>>(W1, w1h, w1l, W2, w2h, w2l, W3, w3h, w3l);

  gemm1_kernel<<<M / 64, 256, 0, stream>>>(x, w1h, w1l, cur1);
  fused_l23_kernel<<<256, 512, 0, stream>>>(cur1, b1, w2h, w2l, b2, w3h, w3l, b3,
                                            beta1, beta2, beta3, thr1, thr2, thr3, out);
}